// Round 4
// baseline (85.014 us; speedup 1.0000x reference)
//
#include <hip/hip_runtime.h>

#define HH 256
#define WW 256
#define CC 64
#define NG 8
#define NE 32
#define THRESH 15.0f

typedef float f32x4 __attribute__((ext_vector_type(4)));

// out layout: feats (8,256,256,65) floats, then mask (8,256,256) floats
#define FEATS_ELEMS ((size_t)NG * HH * WW * 65)
// ws layout: S (256,256,64) pixel-major, maskw (8,256,256), pinfow (8,256,256)
#define S_ELEMS  ((size_t)HH * WW * CC)
#define MP_ELEMS ((size_t)NG * HH * WW)
#define WS_NEEDED ((S_ELEMS + 2 * MP_ELEMS) * sizeof(float) + 16)

// ============================ K1: sample + mask/pinfo ============================
__global__ __launch_bounds__(256) void k1_sample_mask(
    const float* __restrict__ img,    // (64,256,256)
    const float* __restrict__ edges,  // (8,32,4)
    float* __restrict__ out,
    float* __restrict__ S,
    float* __restrict__ maskw,
    float* __restrict__ pinfow)
{
#pragma clang fp contract(off)
    __shared__ float s_buf[130 * 65];   // [(yy*65+x)*65 + c]
    __shared__ float s_e0v[NG * NE], s_e0u[NG * NE];
    __shared__ float s_e1v[NG * NE], s_e1u[NG * NE];
    __shared__ float s_dn0[NG * NE], s_dn1[NG * NE], s_Lm[NG * NE];

    const int tid = threadIdx.x;
    const int u0  = blockIdx.x * 64;
    const int v   = blockIdx.y;

    // ---- Phase A: per-edge precompute
    {
        const float4 e4 = reinterpret_cast<const float4*>(edges)[tid];
        float e0v = e4.x * 256.0f;
        float e0u = e4.y * 256.0f;
        float e1v = e4.z * 256.0f;
        float e1u = e4.w * 256.0f;
        float d0 = e1v - e0v;
        float d1 = e1u - e0u;
        float L  = __fsqrt_rn(d0 * d0 + d1 * d1);
        float Lm = fmaxf(L, 1e-4f);
        s_e0v[tid] = e0v; s_e0u[tid] = e0u;
        s_e1v[tid] = e1v; s_e1u[tid] = e1u;
        s_dn0[tid] = __fdiv_rn(d0, Lm);
        s_dn1[tid] = __fdiv_rn(d1, Lm);
        s_Lm[tid]  = Lm;
    }
    __syncthreads();

    // ---- Phase B: mask + pinfo → ws (+ mask output)
    {
        const int px = tid & 63;
        const float U = (float)(u0 + px);
        const float V = (float)v;
        for (int half = 0; half < 2; ++half) {
            const int g = (tid >> 6) + half * 4;
            float sm = 0.0f, cnt = 0.0f;
            bool any = false;
            for (int e = 0; e < NE; ++e) {
                const int idx = g * NE + e;
                const float diff0 = V - s_e0v[idx];
                const float diff1 = U - s_e0u[idx];
                const float dn0 = s_dn0[idx];
                const float dn1 = s_dn1[idx];
                const float nd = fabsf(diff0 * dn1 + diff1 * (-dn0));
                const float dd = __fdiv_rn(diff0 * dn0 + diff1 * dn1, s_Lm[idx]);
                const float r0 = __fsqrt_rn(diff0 * diff0 + diff1 * diff1);
                const float f0 = V - s_e1v[idx];
                const float f1 = U - s_e1u[idx];
                const float r1 = __fsqrt_rn(f0 * f0 + f1 * f1);
                const bool m = ((nd <= THRESH) && (dd <= 1.0f) && (dd >= 0.0f))
                               || (r0 <= THRESH) || (r1 <= THRESH);
                if (m) {
                    any = true;
                    sm += fminf(dd, 1.0f - dd);
                    cnt += 1.0f;
                }
            }
            const float pf = __fdiv_rn(sm, fmaxf(cnt, 1e-4f));
            const float mv = any ? 1.0f : 0.0f;
            const size_t o = ((size_t)g * HH + v) * WW + (u0 + px);
            maskw[o]  = mv;
            pinfow[o] = pf;
            out[FEATS_ELEMS + o] = mv;
        }
    }

    // ---- Phase C: stage image tile: rows {v-1, v}, cols {u0-1 .. u0+63}, 64 ch.
    {
        for (int i = tid; i < CC * 2 * 65; i += 256) {
            const int c  = i / 130;
            const int r  = i - c * 130;
            const int yy = r / 65;
            const int x  = r - yy * 65;
            const int gy = v - 1 + yy;
            const int gx = u0 - 1 + x;
            float val = 0.0f;
            if (gy >= 0 && gx >= 0) {
                val = img[((size_t)c * HH + gy) * WW + gx];
            }
            s_buf[(yy * 65 + x) * 65 + c] = val;
        }
    }
    __syncthreads();

    // ---- Phase D: sample, store S pixel-major (coalesced 256B per wave-row)
    {
        const int wv   = tid >> 6;
        const int lane = tid & 63;
        const size_t srow = ((size_t)v * WW + u0) * CC;
        #pragma unroll
        for (int i = 0; i < 16; ++i) {
            const int p = wv * 16 + i;
            const float s = s_buf[(p) * 65 + lane] * 0.25f
                          + s_buf[(p + 1) * 65 + lane] * 0.25f
                          + s_buf[(65 + p) * 65 + lane] * 0.25f
                          + s_buf[(66 + p) * 65 + lane] * 0.25f;
            S[srow + (size_t)p * CC + lane] = s;
        }
    }
}

// ============================ K2: barrier-free feats streamer ============================
__global__ __launch_bounds__(256) void k2_stream(
    const float* __restrict__ S,
    const float* __restrict__ maskw,
    const float* __restrict__ pinfow,
    float* __restrict__ out)
{
    const int tid = threadIdx.x;
    const int u0  = blockIdx.x * 64;
    const int v   = blockIdx.y;
    const int g   = blockIdx.z;

    const float* sg = S + ((size_t)v * WW + u0) * CC;
    const float* mg = maskw  + ((size_t)g * HH + v) * WW + u0;
    const float* pg = pinfow + ((size_t)g * HH + v) * WW + u0;
    float* gout = out + (((size_t)g * HH + v) * WW + u0) * 65;

    #pragma unroll
    for (int k = 0; k < 5; ++k) {
        const int q = tid + k * 256;
        if (q < 1040) {
            const int f  = q * 4;
            const int p0 = (int)((unsigned)f / 65u);
            const int b  = (p0 + 1) * 65 - f;      // f+b = start of record p0+1
            const int s0 = f - p0;                 // S index of out[f] (if not pinfo)
            const float v0 = sg[s0];
            const float v1 = sg[s0 + 1];
            const float v2 = sg[s0 + 2];
            const float v3 = sg[s0 + 3];
            const float m0  = mg[p0];
            const float m1  = mg[(b < 4) ? (p0 + 1) : p0];
            const float pi0 = pg[p0];
            // out[f+j]: j==b-1 -> pinfo; j<b-1 -> vec[j]; j>=b -> vec[j-1]
            f32x4 r;
            r.x = ((b == 1) ? pi0 : v0) * ((0 < b) ? m0 : m1);
            r.y = ((b == 2) ? pi0 : ((b == 1) ? v0 : v1)) * ((1 < b) ? m0 : m1);
            r.z = ((b == 3) ? pi0 : ((b <= 2) ? v1 : v2)) * ((2 < b) ? m0 : m1);
            r.w = ((b == 4) ? pi0 : ((b <= 3) ? v2 : v3)) * ((3 < b) ? m0 : m1);
            __builtin_nontemporal_store(r, reinterpret_cast<f32x4*>(&gout[f]));
        }
    }
}

// ============================ Fallback: R2 fused kernel ============================
__global__ __launch_bounds__(256) void fused_sparse_encoder(
    const float* __restrict__ img,
    const float* __restrict__ edges,
    float* __restrict__ out)
{
#pragma clang fp contract(off)
    __shared__ float s_buf[130 * 65];
    __shared__ float s_e0v[NG * NE], s_e0u[NG * NE];
    __shared__ float s_e1v[NG * NE], s_e1u[NG * NE];
    __shared__ float s_dn0[NG * NE], s_dn1[NG * NE], s_Lm[NG * NE];
    __shared__ float s_mask[NG * 64];
    __shared__ float s_pinfo[NG * 64];

    const int tid = threadIdx.x;
    const int u0  = blockIdx.x * 64;
    const int v   = blockIdx.y;

    {
        const float4 e4 = reinterpret_cast<const float4*>(edges)[tid];
        float e0v = e4.x * 256.0f;
        float e0u = e4.y * 256.0f;
        float e1v = e4.z * 256.0f;
        float e1u = e4.w * 256.0f;
        float d0 = e1v - e0v;
        float d1 = e1u - e0u;
        float L  = __fsqrt_rn(d0 * d0 + d1 * d1);
        float Lm = fmaxf(L, 1e-4f);
        s_e0v[tid] = e0v; s_e0u[tid] = e0u;
        s_e1v[tid] = e1v; s_e1u[tid] = e1u;
        s_dn0[tid] = __fdiv_rn(d0, Lm);
        s_dn1[tid] = __fdiv_rn(d1, Lm);
        s_Lm[tid]  = Lm;
    }
    __syncthreads();

    {
        const int px = tid & 63;
        const float U = (float)(u0 + px);
        const float V = (float)v;
        for (int half = 0; half < 2; ++half) {
            const int g = (tid >> 6) + half * 4;
            float sm = 0.0f, cnt = 0.0f;
            bool any = false;
            for (int e = 0; e < NE; ++e) {
                const int idx = g * NE + e;
                const float diff0 = V - s_e0v[idx];
                const float diff1 = U - s_e0u[idx];
                const float dn0 = s_dn0[idx];
                const float dn1 = s_dn1[idx];
                const float nd = fabsf(diff0 * dn1 + diff1 * (-dn0));
                const float dd = __fdiv_rn(diff0 * dn0 + diff1 * dn1, s_Lm[idx]);
                const float r0 = __fsqrt_rn(diff0 * diff0 + diff1 * diff1);
                const float f0 = V - s_e1v[idx];
                const float f1 = U - s_e1u[idx];
                const float r1 = __fsqrt_rn(f0 * f0 + f1 * f1);
                const bool m = ((nd <= THRESH) && (dd <= 1.0f) && (dd >= 0.0f))
                               || (r0 <= THRESH) || (r1 <= THRESH);
                if (m) { any = true; sm += fminf(dd, 1.0f - dd); cnt += 1.0f; }
            }
            const float pf = __fdiv_rn(sm, fmaxf(cnt, 1e-4f));
            const float mv = any ? 1.0f : 0.0f;
            s_mask[g * 64 + px]  = mv;
            s_pinfo[g * 64 + px] = pf;
            out[FEATS_ELEMS + ((size_t)g * HH + v) * WW + (u0 + px)] = mv;
        }
    }

    {
        for (int i = tid; i < CC * 2 * 65; i += 256) {
            const int c  = i / 130;
            const int r  = i - c * 130;
            const int yy = r / 65;
            const int x  = r - yy * 65;
            const int gy = v - 1 + yy;
            const int gx = u0 - 1 + x;
            float val = 0.0f;
            if (gy >= 0 && gx >= 0) val = img[((size_t)c * HH + gy) * WW + gx];
            s_buf[(yy * 65 + x) * 65 + c] = val;
        }
    }
    __syncthreads();

    const int wv   = tid >> 6;
    const int lane = tid & 63;
    float sreg[16];
    #pragma unroll
    for (int i = 0; i < 16; ++i) {
        const int p = wv * 16 + i;
        sreg[i] = s_buf[(p) * 65 + lane] * 0.25f
                + s_buf[(p + 1) * 65 + lane] * 0.25f
                + s_buf[(65 + p) * 65 + lane] * 0.25f
                + s_buf[(66 + p) * 65 + lane] * 0.25f;
    }
    __syncthreads();
    #pragma unroll
    for (int i = 0; i < 16; ++i) {
        const int p = wv * 16 + i;
        s_buf[p * 65 + lane] = sreg[i];
    }
    __syncthreads();

    for (int g = 0; g < NG; ++g) {
        const float* msk = &s_mask[g * 64];
        const float* pin = &s_pinfo[g * 64];
        float* gout = out + (((size_t)g * HH + v) * WW + u0) * 65;
        #pragma unroll
        for (int k = 0; k < 5; ++k) {
            const int q = tid + k * 256;
            if (q < 1040) {
                const int f  = q * 4;
                const int p0 = (int)((unsigned)f / 65u);
                const int b  = (p0 + 1) * 65 - f;
                const float4 tv = *reinterpret_cast<const float4*>(&s_buf[f]);
                const float m0  = msk[p0];
                const float m1  = msk[(b < 4) ? (p0 + 1) : p0];
                const float pi0 = pin[p0];
                float r0 = ((b == 1) ? pi0 : tv.x) * ((0 < b) ? m0 : m1);
                float r1 = ((b == 2) ? pi0 : tv.y) * ((1 < b) ? m0 : m1);
                float r2 = ((b == 3) ? pi0 : tv.z) * ((2 < b) ? m0 : m1);
                float r3 = ((b == 4) ? pi0 : tv.w) * ((3 < b) ? m0 : m1);
                *reinterpret_cast<float4*>(&gout[f]) = make_float4(r0, r1, r2, r3);
            }
        }
    }
}

extern "C" void kernel_launch(void* const* d_in, const int* in_sizes, int n_in,
                              void* d_out, int out_size, void* d_ws, size_t ws_size,
                              hipStream_t stream) {
    const float* img   = (const float*)d_in[0];
    const float* edges = (const float*)d_in[1];
    float* out = (float*)d_out;

    if (ws_size >= WS_NEEDED) {
        float* S      = (float*)d_ws;
        float* maskw  = S + S_ELEMS;
        float* pinfow = maskw + MP_ELEMS;
        dim3 g1(WW / 64, HH);
        k1_sample_mask<<<g1, 256, 0, stream>>>(img, edges, out, S, maskw, pinfow);
        dim3 g2(WW / 64, HH, NG);
        k2_stream<<<g2, 256, 0, stream>>>(S, maskw, pinfow, out);
    } else {
        dim3 grid(WW / 64, HH);
        fused_sparse_encoder<<<grid, 256, 0, stream>>>(img, edges, out);
    }
}

// Round 5
// 40.841 us; speedup vs baseline: 2.0816x; 2.0816x over previous
//
#include <hip/hip_runtime.h>

#define HH 256
#define WW 256
#define CC 64
#define NG 8
#define NE 32
#define PX 32           // pixels per block
#define THRESH 15.0f

// out layout: feats (8,256,256,65) floats, then mask (8,256,256) floats
#define FEATS_ELEMS ((size_t)NG * HH * WW * 65)

// image tile: rows (yy,x): yy in {0,1} (img rows v-1, v), x in [0,33) (cols u0-1..u0+31)
// addr(yy,x,c) = (yy*33 + x)*65 + c   -> 66*65 = 4290 floats
// t tile (reused):  t(p,c) = p*65 + c, p in [0,32), slot c=64 garbage -> 2080 floats
#define IMG_ELEMS (CC * 2 * 33)   // 4224 loaded elements

__global__ __launch_bounds__(256, 5) void fused_sparse_encoder(
    const float* __restrict__ img,    // (64,256,256)
    const float* __restrict__ edges,  // (8,32,4)
    float* __restrict__ out)
{
#pragma clang fp contract(off)
    __shared__ float s_buf[66 * 65];          // 17.2 KB, dual-use (img tile, then t tile)
    __shared__ float s_e0v[NG * NE], s_e0u[NG * NE];
    __shared__ float s_e1v[NG * NE], s_e1u[NG * NE];
    __shared__ float s_dn0[NG * NE], s_dn1[NG * NE], s_Lm[NG * NE];
    __shared__ float s_mask[NG * PX];
    __shared__ float s_pinfo[NG * PX];

    const int tid = threadIdx.x;
    const int u0  = blockIdx.x * PX;
    const int v   = blockIdx.y;

    // ---- Phase A: per-edge precompute (256 threads = 256 edges)
    {
        const float4 e4 = reinterpret_cast<const float4*>(edges)[tid];
        float e0v = e4.x * 256.0f;
        float e0u = e4.y * 256.0f;
        float e1v = e4.z * 256.0f;
        float e1u = e4.w * 256.0f;
        float d0 = e1v - e0v;
        float d1 = e1u - e0u;
        float L  = __fsqrt_rn(d0 * d0 + d1 * d1);
        float Lm = fmaxf(L, 1e-4f);
        s_e0v[tid] = e0v; s_e0u[tid] = e0u;
        s_e1v[tid] = e1v; s_e1u[tid] = e1u;
        s_dn0[tid] = __fdiv_rn(d0, Lm);
        s_dn1[tid] = __fdiv_rn(d1, Lm);
        s_Lm[tid]  = Lm;
    }
    __syncthreads();

    // ---- Phase C-issue: img tile loads into registers (in flight during Phase B)
    float cbuf[17];
    #pragma unroll
    for (int t = 0; t < 17; ++t) {
        const int i = tid + t * 256;
        float val = 0.0f;
        if (i < IMG_ELEMS) {
            const int c  = i / 66;
            const int r  = i - c * 66;
            const int yy = r / 33;
            const int x  = r - yy * 33;
            const int gy = v - 1 + yy;
            const int gx = u0 - 1 + x;
            if (gy >= 0 && gx >= 0) {        // gy<=v<=255, gx<=u0+31<=255 always
                val = img[((size_t)c * HH + gy) * WW + gx];
            }
        }
        cbuf[t] = val;
    }

    // ---- Phase B: mask + pinfo, one (g,px) per thread (overlaps load latency)
    {
        const int px = tid & (PX - 1);
        const int g  = tid >> 5;
        const float U = (float)(u0 + px);
        const float V = (float)v;
        float sm = 0.0f, cnt = 0.0f;
        bool any = false;
        for (int e = 0; e < NE; ++e) {
            const int idx = g * NE + e;
            const float diff0 = V - s_e0v[idx];
            const float diff1 = U - s_e0u[idx];
            const float dn0 = s_dn0[idx];
            const float dn1 = s_dn1[idx];
            const float nd = fabsf(diff0 * dn1 + diff1 * (-dn0));
            const float dd = __fdiv_rn(diff0 * dn0 + diff1 * dn1, s_Lm[idx]);
            const float r0 = __fsqrt_rn(diff0 * diff0 + diff1 * diff1);
            const float f0 = V - s_e1v[idx];
            const float f1 = U - s_e1u[idx];
            const float r1 = __fsqrt_rn(f0 * f0 + f1 * f1);
            const bool m = ((nd <= THRESH) && (dd <= 1.0f) && (dd >= 0.0f))
                           || (r0 <= THRESH) || (r1 <= THRESH);
            if (m) {
                any = true;
                sm += fminf(dd, 1.0f - dd);
                cnt += 1.0f;
            }
        }
        const float pf = __fdiv_rn(sm, fmaxf(cnt, 1e-4f));
        const float mv = any ? 1.0f : 0.0f;
        s_mask[g * PX + px]  = mv;
        s_pinfo[g * PX + px] = pf;
        out[FEATS_ELEMS + ((size_t)g * HH + v) * WW + (u0 + px)] = mv;
    }

    // ---- Phase C-commit: registers -> LDS image tile
    #pragma unroll
    for (int t = 0; t < 17; ++t) {
        const int i = tid + t * 256;
        if (i < IMG_ELEMS) {
            const int c  = i / 66;
            const int r  = i - c * 66;
            const int yy = r / 33;
            const int x  = r - yy * 33;
            s_buf[(yy * 33 + x) * 65 + c] = cbuf[t];
        }
    }
    __syncthreads();

    // ---- Phase D1: 2x2 box sample into registers. Wave wv owns pixels [8*wv, 8*wv+8); lane = channel.
    const int wv   = tid >> 6;
    const int lane = tid & 63;
    float sreg[8];
    #pragma unroll
    for (int i = 0; i < 8; ++i) {
        const int p = wv * 8 + i;
        sreg[i] = s_buf[(p) * 65 + lane] * 0.25f
                + s_buf[(p + 1) * 65 + lane] * 0.25f
                + s_buf[(33 + p) * 65 + lane] * 0.25f
                + s_buf[(34 + p) * 65 + lane] * 0.25f;
    }
    __syncthreads();

    // ---- Phase D2: transpose into t tile (aliases s_buf; slot c=64 left garbage)
    #pragma unroll
    for (int i = 0; i < 8; ++i) {
        const int p = wv * 8 + i;
        s_buf[p * 65 + lane] = sreg[i];
    }
    __syncthreads();

    // ---- Phase E: per g, stream 2080 floats (520 float4), aligned + contiguous.
    for (int g = 0; g < NG; ++g) {
        const float* msk = &s_mask[g * PX];
        const float* pin = &s_pinfo[g * PX];
        float* gout = out + (((size_t)g * HH + v) * WW + u0) * 65;
        #pragma unroll
        for (int k = 0; k < 3; ++k) {
            const int q = tid + k * 256;
            if (q < 520) {
                const int f  = q * 4;
                const int p0 = (int)((unsigned)f / 65u);
                const int b  = (p0 + 1) * 65 - f;   // out[f+j]: j==b-1 -> pinfo(p0); j>=b -> pixel p0+1
                const float4 tv = *reinterpret_cast<const float4*>(&s_buf[f]);
                const float m0  = msk[p0];
                const float m1  = msk[(b < 4) ? (p0 + 1) : p0];
                const float pi0 = pin[p0];
                float r0 = ((b == 1) ? pi0 : tv.x) * ((0 < b) ? m0 : m1);
                float r1 = ((b == 2) ? pi0 : tv.y) * ((1 < b) ? m0 : m1);
                float r2 = ((b == 3) ? pi0 : tv.z) * ((2 < b) ? m0 : m1);
                float r3 = ((b == 4) ? pi0 : tv.w) * ((3 < b) ? m0 : m1);
                *reinterpret_cast<float4*>(&gout[f]) = make_float4(r0, r1, r2, r3);
            }
        }
    }
}

extern "C" void kernel_launch(void* const* d_in, const int* in_sizes, int n_in,
                              void* d_out, int out_size, void* d_ws, size_t ws_size,
                              hipStream_t stream) {
    const float* img   = (const float*)d_in[0];
    const float* edges = (const float*)d_in[1];
    float* out = (float*)d_out;
    dim3 grid(WW / PX, HH);
    fused_sparse_encoder<<<grid, 256, 0, stream>>>(img, edges, out);
}

// Round 6
// 40.392 us; speedup vs baseline: 2.1047x; 1.0111x over previous
//
#include <hip/hip_runtime.h>

#define HH 256
#define WW 256
#define CC 64
#define NG 8
#define NE 32
#define PX 32           // pixels per block
#define THRESH 15.0f

typedef float f32x4 __attribute__((ext_vector_type(4)));

// out layout: feats (8,256,256,65) floats, then mask (8,256,256) floats
#define FEATS_ELEMS ((size_t)NG * HH * WW * 65)

// image tile: (yy,x): yy in {0,1} (img rows v-1, v), x in [0,33) (cols u0-1..u0+31)
// addr(yy,x,c) = (yy*33 + x)*65 + c   -> 66*65 = 4290 floats
// t tile (aliased):  t(p,c) = p*65 + c, p in [0,32) -> first 2080 floats
#define IMG_ELEMS (CC * 2 * 33)   // 4224 loaded elements

__global__ __launch_bounds__(256, 6) void fused_sparse_encoder(
    const float* __restrict__ img,    // (64,256,256)
    const float* __restrict__ edges,  // (8,32,4)
    float* __restrict__ out)
{
#pragma clang fp contract(off)
    __shared__ float  s_buf[66 * 65];     // 17.16 KB, dual-use (img tile, then t tile)
    __shared__ float4 s_k1[NG * NE];      // e0v, e0u, dn0, dn1
    __shared__ float2 s_k2[NG * NE];      // e1v, e1u
    __shared__ float  s_k3[NG * NE];      // Lm
    __shared__ float  s_mask[NG * PX];
    __shared__ float  s_pinfo[NG * PX];

    const int tid = threadIdx.x;
    const int u0  = blockIdx.x * PX;
    const int v   = blockIdx.y;

    // ---- Phase A: per-edge precompute (256 threads = 256 edges)
    {
        const float4 e4 = reinterpret_cast<const float4*>(edges)[tid];
        const float e0v = e4.x * 256.0f;
        const float e0u = e4.y * 256.0f;
        const float e1v = e4.z * 256.0f;
        const float e1u = e4.w * 256.0f;
        const float d0 = e1v - e0v;
        const float d1 = e1u - e0u;
        const float L  = __fsqrt_rn(d0 * d0 + d1 * d1);
        const float Lm = fmaxf(L, 1e-4f);
        s_k1[tid] = make_float4(e0v, e0u, __fdiv_rn(d0, Lm), __fdiv_rn(d1, Lm));
        s_k2[tid] = make_float2(e1v, e1u);
        s_k3[tid] = Lm;
    }
    __syncthreads();

    // ---- Phase C-issue: img tile loads into registers (in flight during Phase B)
    float cbuf[17];
    #pragma unroll
    for (int t = 0; t < 17; ++t) {
        const int i = tid + t * 256;
        float val = 0.0f;
        if (i < IMG_ELEMS) {
            const int c  = i / 66;
            const int r  = i - c * 66;
            const int yy = r / 33;
            const int x  = r - yy * 33;
            const int gy = v - 1 + yy;
            const int gx = u0 - 1 + x;
            if (gy >= 0 && gx >= 0) {        // gy<=255, gx<=255 always
                val = img[((size_t)c * HH + gy) * WW + gx];
            }
        }
        cbuf[t] = val;
    }

    // ---- Phase B: mask + pinfo, one (g,px) per thread (overlaps load latency)
    {
        const int px = tid & (PX - 1);
        const int g  = tid >> 5;
        const float U = (float)(u0 + px);
        const float V = (float)v;
        float sm = 0.0f, cnt = 0.0f;
        bool any = false;
        for (int e = 0; e < NE; ++e) {
            const int idx = g * NE + e;
            const float4 k1 = s_k1[idx];
            const float2 k2 = s_k2[idx];
            const float  Lm = s_k3[idx];
            const float diff0 = V - k1.x;
            const float diff1 = U - k1.y;
            // nd = |diff0*dn1 + diff1*(-dn0)|  (exact ref sequence)
            const float ndv = diff0 * k1.w - diff1 * k1.z;
            // dd = (diff0*dn0 + diff1*dn1) / Lm  (exact ref sequence)
            const float ddn = diff0 * k1.z + diff1 * k1.w;
            const float dd  = __fdiv_rn(ddn, Lm);
            // sqrt(r2) <= 15  <=>  r2 <= 225  (exact predicate equivalence)
            const float r0sq = diff0 * diff0 + diff1 * diff1;
            const float f0 = V - k2.x;
            const float f1 = U - k2.y;
            const float r1sq = f0 * f0 + f1 * f1;
            const bool m = ((fabsf(ndv) <= THRESH) && (dd <= 1.0f) && (dd >= 0.0f))
                           || (r0sq <= 225.0f) || (r1sq <= 225.0f);
            if (m) {
                any = true;
                sm += fminf(dd, 1.0f - dd);
                cnt += 1.0f;
            }
        }
        const float pf = __fdiv_rn(sm, fmaxf(cnt, 1e-4f));
        const float mv = any ? 1.0f : 0.0f;
        s_mask[g * PX + px]  = mv;
        s_pinfo[g * PX + px] = pf;
        out[FEATS_ELEMS + ((size_t)g * HH + v) * WW + (u0 + px)] = mv;
    }

    // ---- Phase C-commit: registers -> LDS image tile
    #pragma unroll
    for (int t = 0; t < 17; ++t) {
        const int i = tid + t * 256;
        if (i < IMG_ELEMS) {
            const int c  = i / 66;
            const int r  = i - c * 66;
            const int yy = r / 33;
            const int x  = r - yy * 33;
            s_buf[(yy * 33 + x) * 65 + c] = cbuf[t];
        }
    }
    __syncthreads();

    // ---- Phase D1: 2x2 box sample into registers. Wave wv owns pixels [8*wv, 8*wv+8); lane = channel.
    const int wv   = tid >> 6;
    const int lane = tid & 63;
    float sreg[8];
    #pragma unroll
    for (int i = 0; i < 8; ++i) {
        const int p = wv * 8 + i;
        sreg[i] = s_buf[(p) * 65 + lane] * 0.25f
                + s_buf[(p + 1) * 65 + lane] * 0.25f
                + s_buf[(33 + p) * 65 + lane] * 0.25f
                + s_buf[(34 + p) * 65 + lane] * 0.25f;
    }
    __syncthreads();

    // ---- Phase D2: transpose into t tile (aliases s_buf; slot c=64 left garbage)
    #pragma unroll
    for (int i = 0; i < 8; ++i) {
        const int p = wv * 8 + i;
        s_buf[p * 65 + lane] = sreg[i];
    }
    __syncthreads();

    // ---- Phase E: per g, stream 2080 floats (520 float4), aligned + contiguous.
    for (int g = 0; g < NG; ++g) {
        const float* msk = &s_mask[g * PX];
        const float* pin = &s_pinfo[g * PX];
        float* gout = out + (((size_t)g * HH + v) * WW + u0) * 65;
        #pragma unroll
        for (int k = 0; k < 3; ++k) {
            const int q = tid + k * 256;
            if (q < 520) {
                const int f  = q * 4;
                const int p0 = (int)((unsigned)f / 65u);
                const int b  = (p0 + 1) * 65 - f;   // out[f+j]: j==b-1 -> pinfo(p0); j>=b -> pixel p0+1
                const float4 tv = *reinterpret_cast<const float4*>(&s_buf[f]);
                const float m0  = msk[p0];
                const float m1  = msk[(b < 4) ? (p0 + 1) : p0];
                const float pi0 = pin[p0];
                f32x4 r;
                r.x = ((b == 1) ? pi0 : tv.x) * ((0 < b) ? m0 : m1);
                r.y = ((b == 2) ? pi0 : tv.y) * ((1 < b) ? m0 : m1);
                r.z = ((b == 3) ? pi0 : tv.z) * ((2 < b) ? m0 : m1);
                r.w = ((b == 4) ? pi0 : tv.w) * ((3 < b) ? m0 : m1);
                __builtin_nontemporal_store(r, reinterpret_cast<f32x4*>(&gout[f]));
            }
        }
    }
}

extern "C" void kernel_launch(void* const* d_in, const int* in_sizes, int n_in,
                              void* d_out, int out_size, void* d_ws, size_t ws_size,
                              hipStream_t stream) {
    const float* img   = (const float*)d_in[0];
    const float* edges = (const float*)d_in[1];
    float* out = (float*)d_out;
    dim3 grid(WW / PX, HH);
    fused_sparse_encoder<<<grid, 256, 0, stream>>>(img, edges, out);
}